// Round 3
// baseline (366.776 us; speedup 1.0000x reference)
//
#include <hip/hip_runtime.h>

// Superpixel max-pool: out[b][c][k] = max over pixels with spx[b,h,w]==k of img[b][c][h,w].
// LDS privatization, exclusive output ownership (512 blocks = 8 batches x 64 channel-pairs).
//
// R1: bare ds_max atomics -> 359 us. R2: read-test + exec-masked atomic -> 359 us (unchanged!).
// => LDS atomic cost is ~210 cyc per INSTRUCTION regardless of active lanes; plain LDS reads
//    are ~free (R2 added 4096 random ds_read/CU for +0.3%). So the fix is fewer atomic
//    INSTRUCTIONS: ballot-compact the ~6% truly-improving candidates into a per-wave LDS
//    stack (plain coalesced b64 writes, unique slots), drain with DENSE 64-lane atomics.
//    Expected atomic instrs/block: 2048 -> ~300 (iter0 seed + compacted drains).

#define NTHREADS 1024

constexpr int B_ = 8, C_ = 128, H_ = 256, W_ = 256, K_ = 1024;
constexpr int HW_ = H_ * W_;        // 65536
constexpr int CSUB = 2;             // channels per block
constexpr int CGRP = C_ / CSUB;     // 64 channel-groups per batch
constexpr int STRIDE = 2;           // both channels of a label adjacent -> one ds_read_b64 test
constexpr int NWAVES = NTHREADS / 64;
constexpr int QCAP = 256;           // per-wave stack entries (8 B each)

// order-preserving float<->uint: monotone, so uint max == float max (bitwise exact)
__device__ __forceinline__ unsigned f2o(float f) {
    unsigned u = __float_as_uint(f);
    return u ^ (unsigned)(((int)u >> 31) | (int)0x80000000);
}
__device__ __forceinline__ float o2f(unsigned o) {
    return __uint_as_float(o ^ (((int)o >= 0) ? 0xFFFFFFFFu : 0x80000000u));
}

__global__ __launch_bounds__(NTHREADS) void SupPixPool_25366076850473_kernel(
    const float* __restrict__ img, const int* __restrict__ spx, float* __restrict__ out)
{
    __shared__ unsigned smax[K_ * STRIDE];            // 8 KB
    __shared__ unsigned long long q[NWAVES * QCAP];   // 32 KB -> total 40 KB, 2 blocks/CU
    const int tid = threadIdx.x, lane = tid & 63, wid = tid >> 6;
    const int qbase = wid * QCAP;
    const unsigned long long lmask = (1ull << lane) - 1ull;

    // init to f2o(-inf) = 0x007FFFFF so empty segments produce -inf (segment_max semantics)
    for (int i = tid; i < K_ * STRIDE; i += NTHREADS)
        smax[i] = 0x007FFFFFu;
    __syncthreads();

    const int b  = blockIdx.x / CGRP;
    const int cg = blockIdx.x % CGRP;
    const int c0 = cg * CSUB;

    const int4*   lab4 = (const int4*)(spx + (size_t)b * HW_);
    const float4* img0 = (const float4*)(img + ((size_t)(b * C_ + c0)) * HW_);
    const float4* img1 = (const float4*)(img + ((size_t)(b * C_ + c0 + 1)) * HW_);
    constexpr int NV = HW_ / 4;                       // 16384 -> exactly 16 iters/thread

    int qcount = 0;                                   // wave-uniform (ballot-derived)

    for (int v = tid, it = 0; v < NV; v += NTHREADS, ++it) {
        int4 lab = lab4[v];
        float4 x0 = img0[v], x1 = img1[v];
        int a[4] = { lab.x * STRIDE, lab.y * STRIDE, lab.z * STRIDE, lab.w * STRIDE };
        unsigned o[8] = { f2o(x0.x), f2o(x0.y), f2o(x0.z), f2o(x0.w),
                          f2o(x1.x), f2o(x1.y), f2o(x1.z), f2o(x1.w) };
        if (it == 0) {
            // seed pass: table is all -inf, everything "passes" -> direct atomics
#pragma unroll
            for (int j = 0; j < 4; ++j) {
                atomicMax(&smax[a[j]],     o[j]);
                atomicMax(&smax[a[j] + 1], o[j + 4]);
            }
        } else {
            // cheap plain-read test: both channels of a label in one aligned b64 read
            uint2 cur[4];
#pragma unroll
            for (int j = 0; j < 4; ++j)
                cur[j] = *(const uint2*)&smax[a[j]];
#pragma unroll
            for (int j = 0; j < 8; ++j) {
                int aj = a[j & 3] + (j >> 2);
                unsigned cj = (j < 4) ? cur[j & 3].x : cur[j & 3].y;
                bool pass = o[j] > cj;
                unsigned long long m = __ballot(pass);
                if (m) {                              // wave-uniform
                    int cnt = __popcll(m);
                    if (qcount + cnt <= QCAP) {
                        if (pass) {
                            int pos = qbase + qcount + __popcll(m & lmask);
                            q[pos] = ((unsigned long long)o[j] << 32) | (unsigned)aj;
                        }
                        qcount += cnt;
                    } else {
                        // stack full (rare, early iters) -> direct atomic, still correct
                        if (pass) atomicMax(&smax[aj], o[j]);
                    }
                }
            }
            // drain in dense 64-lane batches (LIFO stack)
            while (qcount >= 64) {
                qcount -= 64;
                unsigned long long e = q[qbase + qcount + lane];
                atomicMax(&smax[(unsigned)(e & 0xFFFFFFFFu)], (unsigned)(e >> 32));
            }
        }
    }
    // final flush of the partial batch
    if (lane < qcount) {
        unsigned long long e = q[qbase + lane];
        atomicMax(&smax[(unsigned)(e & 0xFFFFFFFFu)], (unsigned)(e >> 32));
    }
    __syncthreads();

    // exclusive epilogue: this block owns out[b][c0..c0+CSUB)[*]
    float* outb = out + ((size_t)(b * C_ + c0)) * K_;
    for (int i = tid; i < K_ * CSUB; i += NTHREADS) {
        int c = i >> 10;                              // K_ = 1024
        int k = i & (K_ - 1);
        outb[c * K_ + k] = o2f(smax[k * STRIDE + c]); // stride-2 lanes: 2-way alias, free
    }
}

extern "C" void kernel_launch(void* const* d_in, const int* in_sizes, int n_in,
                              void* d_out, int out_size, void* d_ws, size_t ws_size,
                              hipStream_t stream) {
    const float* img = (const float*)d_in[0];
    const int*   spx = (const int*)d_in[1];
    float*       out = (float*)d_out;                 // fp32 output, [B][C][K]
    dim3 grid(B_ * CGRP);                             // 512 blocks
    hipLaunchKernelGGL(SupPixPool_25366076850473_kernel, grid, dim3(NTHREADS), 0, stream,
                       img, spx, out);
}

// Round 5
// 342.858 us; speedup vs baseline: 1.0698x; 1.0698x over previous
//
#include <hip/hip_runtime.h>

// Superpixel max-pool: out[b][c][k] = max over pixels with spx[b,h,w]==k of img[b][c][h,w].
// LDS privatization, exclusive output ownership (512 blocks = 8 batches x 64 channel-pairs;
// each block owns out[b][c0:c0+2][:] -> no global atomics, no init pass).
//
// Session evidence (R1-R3): kernel dispatch never appears in rocprof top-5 (all 5 are the
// harness's 1 GiB d_ws re-poison fills @160us) => kernel itself is ~55us of the ~359us
// metric; the rest is fixed restore/poison overhead (160 ws-fill + ~83 input restore).
// LDS atomics are NOT the bottleneck: masking 94% of lanes (R2) and cutting atomic instr
// count 8x via ballot-compaction (R3) both changed nothing / regressed. Kernel is at
// ~78% of the 43us pure-stream floor (268 MB img). This round: direct-atomic R1 structure
// + 2x unroll with batched loads (deeper VMEM pipeline) + nontemporal img loads (img has
// zero reuse; labels are reused by 64 blocks and should stay in L2).
// R4 fix: __builtin_nontemporal_load needs native clang vectors, not HIP_vector_type.

#define NTHREADS 1024

constexpr int B_ = 8, C_ = 128, H_ = 256, W_ = 256, K_ = 1024;
constexpr int HW_ = H_ * W_;        // 65536
constexpr int CSUB = 2;             // channels per block
constexpr int CGRP = C_ / CSUB;     // 64 channel-groups per batch
constexpr int STRIDE = 3;           // odd -> (label*3+c)%32 spreads all 32 LDS banks

typedef float  fx4 __attribute__((ext_vector_type(4)));  // native vec: ok for nontemporal
typedef int    ix4 __attribute__((ext_vector_type(4)));

// order-preserving float<->uint: monotone, so uint max == float max (bitwise exact)
__device__ __forceinline__ unsigned f2o(float f) {
    unsigned u = __float_as_uint(f);
    return u ^ (unsigned)(((int)u >> 31) | (int)0x80000000);
}
__device__ __forceinline__ float o2f(unsigned o) {
    return __uint_as_float(o ^ (((int)o >= 0) ? 0xFFFFFFFFu : 0x80000000u));
}

__global__ __launch_bounds__(NTHREADS) void SupPixPool_25366076850473_kernel(
    const float* __restrict__ img, const int* __restrict__ spx, float* __restrict__ out)
{
    __shared__ unsigned smax[K_ * STRIDE];   // 12 KB -> 2 blocks/CU, 32 waves/CU
    const int tid = threadIdx.x;

    // init to f2o(-inf) = 0x007FFFFF so empty segments produce -inf (segment_max semantics)
    for (int i = tid; i < K_ * STRIDE; i += NTHREADS)
        smax[i] = 0x007FFFFFu;
    __syncthreads();

    const int b  = blockIdx.x / CGRP;
    const int cg = blockIdx.x % CGRP;
    const int c0 = cg * CSUB;

    const ix4* lab4 = (const ix4*)(spx + (size_t)b * HW_);
    const fx4* img0 = (const fx4*)(img + ((size_t)(b * C_ + c0)) * HW_);
    const fx4* img1 = (const fx4*)(img + ((size_t)(b * C_ + c0 + 1)) * HW_);
    constexpr int NV = HW_ / 4;              // 16384 vec4 groups; 16 strides -> 8 unroll-2 iters

    for (int v = tid; v < NV; v += 2 * NTHREADS) {
        const int v2 = v + NTHREADS;
        // batch all 6 vector loads up-front so vmcnt waits pipeline across both halves
        ix4 labA = lab4[v];
        ix4 labB = lab4[v2];
        fx4 xA0  = __builtin_nontemporal_load(&img0[v]);
        fx4 xA1  = __builtin_nontemporal_load(&img1[v]);
        fx4 xB0  = __builtin_nontemporal_load(&img0[v2]);
        fx4 xB1  = __builtin_nontemporal_load(&img1[v2]);

        int aA0 = labA.x * STRIDE, aA1 = labA.y * STRIDE,
            aA2 = labA.z * STRIDE, aA3 = labA.w * STRIDE;
        atomicMax(&smax[aA0],     f2o(xA0.x));
        atomicMax(&smax[aA1],     f2o(xA0.y));
        atomicMax(&smax[aA2],     f2o(xA0.z));
        atomicMax(&smax[aA3],     f2o(xA0.w));
        atomicMax(&smax[aA0 + 1], f2o(xA1.x));
        atomicMax(&smax[aA1 + 1], f2o(xA1.y));
        atomicMax(&smax[aA2 + 1], f2o(xA1.z));
        atomicMax(&smax[aA3 + 1], f2o(xA1.w));

        int aB0 = labB.x * STRIDE, aB1 = labB.y * STRIDE,
            aB2 = labB.z * STRIDE, aB3 = labB.w * STRIDE;
        atomicMax(&smax[aB0],     f2o(xB0.x));
        atomicMax(&smax[aB1],     f2o(xB0.y));
        atomicMax(&smax[aB2],     f2o(xB0.z));
        atomicMax(&smax[aB3],     f2o(xB0.w));
        atomicMax(&smax[aB0 + 1], f2o(xB1.x));
        atomicMax(&smax[aB1 + 1], f2o(xB1.y));
        atomicMax(&smax[aB2 + 1], f2o(xB1.z));
        atomicMax(&smax[aB3 + 1], f2o(xB1.w));
    }
    __syncthreads();

    // exclusive epilogue: this block owns out[b][c0..c0+CSUB)[*]
    float* outb = out + ((size_t)(b * C_ + c0)) * K_;
    for (int i = tid; i < K_ * CSUB; i += NTHREADS) {
        int c = i >> 10;                     // K_ = 1024
        int k = i & (K_ - 1);
        outb[c * K_ + k] = o2f(smax[k * STRIDE + c]);
    }
}

extern "C" void kernel_launch(void* const* d_in, const int* in_sizes, int n_in,
                              void* d_out, int out_size, void* d_ws, size_t ws_size,
                              hipStream_t stream) {
    const float* img = (const float*)d_in[0];
    const int*   spx = (const int*)d_in[1];
    float*       out = (float*)d_out;        // fp32 output, [B][C][K]
    dim3 grid(B_ * CGRP);                    // 512 blocks -> 2 blocks/CU
    hipLaunchKernelGGL(SupPixPool_25366076850473_kernel, grid, dim3(NTHREADS), 0, stream,
                       img, spx, out);
}